// Round 10
// baseline (352.811 us; speedup 1.0000x reference)
//
#include <hip/hip_runtime.h>
#include <hip/hip_bf16.h>
#include <hip/hip_fp16.h>

#define B_ 32
#define T_ 2048
#define D_ 1024
#define U_ 1024
#define M_ (B_ * T_)   // 65536
#define NT_ 16         // U_/64 col slabs

typedef _Float16 f16x8 __attribute__((ext_vector_type(8)));
typedef float f32x4 __attribute__((ext_vector_type(4)));
typedef float f32x16 __attribute__((ext_vector_type(16)));

__device__ __forceinline__ float fast_tanh(float x) {
    float xc = fminf(fmaxf(x, -10.f), 10.f);
    float e = __expf(2.f * xc);
    return 1.f - 2.f / (e + 1.f);
}

__device__ __forceinline__ void load_lds16(const void* g, void* l) {
    __builtin_amdgcn_global_load_lds(
        (const __attribute__((address_space(1))) void*)g,
        (__attribute__((address_space(3))) void*)l, 16, 0, 0);
}

// ---- precastT v3: features [M][D] f32 -> featT2 [M/32][D/16][64 lanes x 16B] f16
// Lane order: unit l holds row=l&31, khalf=l>>5 (k = k16*16 + khalf*8 + j).
// One A-frag load in GEMM = 1KB contiguous per wave.
__global__ void precastT_kernel(const float* __restrict__ in,
                                _Float16* __restrict__ out) {
    __shared__ __align__(16) _Float16 lds[32 * 1024];   // 64 KB: [32 rows][128 units]
    int mt = blockIdx.x;              // 2048 tiles of 32 rows
    int t = threadIdx.x;              // 256
    const float* src = in + (size_t)mt * 32 * 1024;
    #pragma unroll
    for (int i = 0; i < 16; ++i) {
        int idx = (i * 256 + t) * 8;          // f32 index 0..32767
        int row = idx >> 10, k = idx & 1023;
        f32x4 a = *(const f32x4*)(src + idx);
        f32x4 b = *(const f32x4*)(src + idx + 4);
        f16x8 h;
        h[0]=(_Float16)a[0]; h[1]=(_Float16)a[1]; h[2]=(_Float16)a[2]; h[3]=(_Float16)a[3];
        h[4]=(_Float16)b[0]; h[5]=(_Float16)b[1]; h[6]=(_Float16)b[2]; h[7]=(_Float16)b[3];
        int u = k >> 3;                       // 0..127
        *(f16x8*)((char*)lds + row * 2048 + ((u ^ (row & 15)) << 4)) = h;
    }
    __syncthreads();
    char* dst = (char*)out + (size_t)mt * 65536;
    #pragma unroll
    for (int i = 0; i < 16; ++i) {
        int o = i * 4096 + t * 16;            // byte offset 0..65535
        int k16 = o >> 10;
        int l = (o >> 4) & 63;
        int row = l & 31, khalf = l >> 5;
        int u = k16 * 2 + khalf;
        f16x8 h = *(const f16x8*)((char*)lds + row * 2048 + ((u ^ (row & 15)) << 4));
        *(f16x8*)(dst + o) = h;
    }
}

// ---- W1 [D][U] f32 -> W1T2 [U/32][D/16][64 lanes x 16B] f16 (same lane order) ----
__global__ void transpose_cast_W1T_kernel(const float* __restrict__ W1,
                                          _Float16* __restrict__ W1T) {
    int u = blockIdx.x * 256 + threadIdx.x;   // grid.x = 4
    int d0 = blockIdx.y * 64;                 // grid.y = 16
    char* base = (char*)W1T + (size_t)(u >> 5) * 65536 + (u & 31) * 16;
    for (int j8 = 0; j8 < 8; ++j8) {
        int k = d0 + j8 * 8;
        f16x8 h;
        #pragma unroll
        for (int j = 0; j < 8; ++j)
            h[j] = (_Float16)W1[(size_t)(k + j) * U_ + u];
        int k16 = k >> 4, khalf = (k >> 3) & 1;
        *(f16x8*)(base + k16 * 1024 + khalf * 512) = h;
    }
}

// ---------------- proj_h ----------------
__global__ void proj_h_partial_kernel(const float* __restrict__ hidden,
                                      const float* __restrict__ W2,
                                      float* __restrict__ pph) {
    int u = blockIdx.x * 256 + threadIdx.x;   // grid.x = 4
    int c = blockIdx.y;                       // grid.y = 8
    __shared__ float hb[32][128];
    for (int i = threadIdx.x; i < 32 * 128; i += 256)
        hb[i >> 7][i & 127] = hidden[(i >> 7) * D_ + c * 128 + (i & 127)];
    __syncthreads();
    float acc[32] = {};
    for (int d = 0; d < 128; ++d) {
        float w = W2[(size_t)(c * 128 + d) * U_ + u];
        #pragma unroll
        for (int b = 0; b < 32; ++b) acc[b] = fmaf(hb[b][d], w, acc[b]);
    }
    #pragma unroll
    for (int b = 0; b < 32; ++b)
        pph[((size_t)c * 32 + b) * U_ + u] = acc[b];
}

__global__ void proj_h_combine_kernel(const float* __restrict__ pph,
                                      const float* __restrict__ b1,
                                      const float* __restrict__ b2,
                                      float* __restrict__ ph) {
    int u = blockIdx.x * 256 + threadIdx.x;
    float bias = b1[u] + b2[u];
    for (int b = 0; b < 32; ++b) {
        float s = bias;
        #pragma unroll
        for (int c = 0; c < 8; ++c) s += pph[((size_t)c * 32 + b) * U_ + u];
        ph[b * U_ + u] = s;
    }
}

// ============ v9: barrier-free GEMM, 32x32x16 MFMA, full dbuf ============
// Grid 1024 (1 block/CU, 4 rounds), 1024 thr = 16 waves -> 4 waves/SIMD.
// Block: 64 u (nt) x 1024 rows (mg). Wave: 64 rows x 64 u = 2x2 32-tiles.
// B: W1T2 slab (128KB) LDS-resident (linear copy, frag-order = 1KB/wave reads).
// A: featT2 lane-ordered tiles -> regs, af+bf double-buffered, K-16 steps.

#define SB0 __builtin_amdgcn_sched_barrier(0);

#define LOAD_AF(dst, s16) do { \
    dst[0] = *(const f16x8*)(aT + (s16) * 1024); \
    dst[1] = *(const f16x8*)(aT + 65536 + (s16) * 1024); \
} while (0)

#define READ_BF(dst, s16) do { \
    dst[0] = *(const f16x8*)(lB + (s16) * 1024 + l16); \
    dst[1] = *(const f16x8*)(lB + 65536 + (s16) * 1024 + l16); \
} while (0)

#define MFMA4(AF, BF) do { \
    __builtin_amdgcn_s_setprio(1); \
    acc[0][0] = __builtin_amdgcn_mfma_f32_32x32x16_f16(AF[0], BF[0], acc[0][0], 0, 0, 0); \
    acc[0][1] = __builtin_amdgcn_mfma_f32_32x32x16_f16(AF[0], BF[1], acc[0][1], 0, 0, 0); \
    acc[1][0] = __builtin_amdgcn_mfma_f32_32x32x16_f16(AF[1], BF[0], acc[1][0], 0, 0, 0); \
    acc[1][1] = __builtin_amdgcn_mfma_f32_32x32x16_f16(AF[1], BF[1], acc[1][1], 0, 0, 0); \
    __builtin_amdgcn_s_setprio(0); \
} while (0)

__global__ __launch_bounds__(1024, 4)
void gemm_logits_v9_kernel(const _Float16* __restrict__ featT2,
                           const _Float16* __restrict__ W1T2,
                           const float* __restrict__ ph,
                           const float* __restrict__ V,
                           float* __restrict__ part)   // [NT_][M]
{
    __shared__ __align__(16) _Float16 Bs[65536];   // 128 KB

    int bid = blockIdx.x;                   // 1024
    int xcd = bid & 7, local = bid >> 3;    // local 0..127
    int nt = local & 15;                    // 0..15 (64-col slab)
    int mg = xcd * 8 + (local >> 4);        // 0..63 (1024-row group)

    int tid = threadIdx.x;
    int l = tid & 63, w = tid >> 6;         // 16 waves
    int l16 = l * 16;
    int l31 = l & 31, hi = l >> 5;
    const char* lB = (const char*)Bs;

    // ---- B prologue: stage 128KB W1T2 slab, linear ----
    {
        const char* src = (const char*)W1T2 + (size_t)nt * 131072;
        #pragma unroll
        for (int i = 0; i < 8; ++i)
            load_lds16(src + i * 16384 + tid * 16, (char*)Bs + i * 16384 + tid * 16);
    }

    // wave's 2 A-tiles (32 rows each): tiles mg*32 + w*2 + {0,1}
    const char* aT = (const char*)featT2 + ((size_t)(mg * 32 + w * 2) << 16) + l16;

    f16x8 afA[2], afB[2], bfA[2], bfB[2];
    f32x16 acc[2][2] = {};

    LOAD_AF(afA, 0);

    float Vv[2], phv[2];
    const float* phb = ph + (mg >> 1) * U_;
    #pragma unroll
    for (int n = 0; n < 2; ++n) {
        int u = nt * 64 + n * 32 + l31;
        Vv[n] = V[u];
        phv[n] = phb[u];
    }

    asm volatile("s_waitcnt vmcnt(0)" ::: "memory");
    __builtin_amdgcn_s_barrier();   // the only block-wide barrier

    READ_BF(bfA, 0);

    #pragma unroll 1
    for (int s = 0; s < 64; s += 2) {
        LOAD_AF(afB, s + 1);
        READ_BF(bfB, s + 1);
        SB0
        MFMA4(afA, bfA);
        SB0
        if (s < 62) {
            LOAD_AF(afA, s + 2);
            READ_BF(bfA, s + 2);
        }
        SB0
        MFMA4(afB, bfB);
        SB0
    }

    // ---- epilogue: s = tanh(acc + ph), partial = sum_u s*V ----
    // C/D 32x32 (r6-verified): col = l&31, row = (reg&3) + 8*(reg>>2) + 4*hi
    int row0 = mg * 1024 + w * 64;
    #pragma unroll
    for (int m = 0; m < 2; ++m) {
        #pragma unroll
        for (int reg = 0; reg < 16; ++reg) {
            float p = fmaf(fast_tanh(acc[m][0][reg] + phv[0]), Vv[0],
                           fast_tanh(acc[m][1][reg] + phv[1]) * Vv[1]);
            p += __shfl_xor(p, 1, 64);
            p += __shfl_xor(p, 2, 64);
            p += __shfl_xor(p, 4, 64);
            p += __shfl_xor(p, 8, 64);
            p += __shfl_xor(p, 16, 64);
            if (l31 == 0) {
                int row = row0 + m * 32 + (reg & 3) + 8 * (reg >> 2) + 4 * hi;
                part[(size_t)nt * M_ + row] = p;
            }
        }
    }
}

// ---------------- softmax over T per batch ----------------
__global__ void softmax_kernel(const float* __restrict__ part,
                               float* __restrict__ wout) {
    int b = blockIdx.x;
    int tid = threadIdx.x;
    __shared__ float red[8];
    float lg[8];
    #pragma unroll
    for (int j = 0; j < 8; ++j) {
        int t = tid + j * 256;
        float s = 0.f;
        #pragma unroll
        for (int p = 0; p < NT_; ++p)
            s += part[(size_t)p * M_ + b * T_ + t];
        lg[j] = s;
    }
    float mx = lg[0];
    #pragma unroll
    for (int j = 1; j < 8; ++j) mx = fmaxf(mx, lg[j]);
    #pragma unroll
    for (int off = 1; off < 64; off <<= 1) mx = fmaxf(mx, __shfl_xor(mx, off, 64));
    int wv = tid >> 6;
    if ((tid & 63) == 0) red[wv] = mx;
    __syncthreads();
    mx = fmaxf(fmaxf(red[0], red[1]), fmaxf(red[2], red[3]));
    float e[8];
    float sum = 0.f;
    #pragma unroll
    for (int j = 0; j < 8; ++j) { e[j] = __expf(lg[j] - mx); sum += e[j]; }
    #pragma unroll
    for (int off = 1; off < 64; off <<= 1) sum += __shfl_xor(sum, off, 64);
    if ((tid & 63) == 0) red[4 + wv] = sum;
    __syncthreads();
    sum = red[4] + red[5] + red[6] + red[7];
    float inv = 1.f / sum;
    #pragma unroll
    for (int j = 0; j < 8; ++j)
        wout[b * T_ + tid + j * 256] = e[j] * inv;
}

// ---- context from featT2: grid (32 b, 8 dc), coalesced 1KB wave reads ----
__global__ void context_v8_kernel(const _Float16* __restrict__ featT2,
                                  const float* __restrict__ w,
                                  float* __restrict__ ctx) {
    int b = blockIdx.x;        // 32
    int dc = blockIdx.y;       // 8 (128 d each)
    int t = threadIdx.x;       // 256 = 4 waves
    __shared__ float wLds[2048];
    for (int i = t; i < 2048; i += 256) wLds[i] = w[b * T_ + i];
    __syncthreads();

    int l = t & 63, g = t >> 6;          // g 0..3
    int row = l & 31, khalf = l >> 5;
    #pragma unroll
    for (int pass = 0; pass < 2; ++pass) {
        int k16 = dc * 8 + pass * 4 + g;
        const char* base = (const char*)featT2 + ((size_t)(b * 64) << 16)
                         + k16 * 1024 + l * 16;
        float acc[8] = {};
        #pragma unroll 4
        for (int mt = 0; mt < 64; ++mt) {
            f16x8 v = *(const f16x8*)(base + ((size_t)mt << 16));
            float wt = wLds[mt * 32 + row];
            #pragma unroll
            for (int j = 0; j < 8; ++j) acc[j] = fmaf(wt, (float)v[j], acc[j]);
        }
        #pragma unroll
        for (int j = 0; j < 8; ++j) {
            acc[j] += __shfl_xor(acc[j], 1, 64);
            acc[j] += __shfl_xor(acc[j], 2, 64);
            acc[j] += __shfl_xor(acc[j], 4, 64);
            acc[j] += __shfl_xor(acc[j], 8, 64);
            acc[j] += __shfl_xor(acc[j], 16, 64);
        }
        if (row == 0) {
            float* o = ctx + b * D_ + k16 * 16 + khalf * 8;
            #pragma unroll
            for (int j = 0; j < 8; ++j) o[j] = acc[j];
        }
    }
}

extern "C" void kernel_launch(void* const* d_in, const int* in_sizes, int n_in,
                              void* d_out, int out_size, void* d_ws, size_t ws_size,
                              hipStream_t stream) {
    const float* features = (const float*)d_in[0];
    const float* hidden   = (const float*)d_in[1];
    const float* W1       = (const float*)d_in[2];
    const float* b1       = (const float*)d_in[3];
    const float* W2       = (const float*)d_in[4];
    const float* b2       = (const float*)d_in[5];
    const float* V        = (const float*)d_in[6];
    // bV drops out of softmax (shift-invariant).

    float* ctx_out = (float*)d_out;            // [B,D]
    float* w_out   = ctx_out + B_ * D_;        // [B,T,1]

    char* ws = (char*)d_ws;
    _Float16* W1T  = (_Float16*)ws;                               // 2 MB @ 0
    float* ph      = (float*)(ws + (size_t)(2 << 20));            // 128 KB @ 2M
    float* pph     = (float*)(ws + (size_t)(2 << 20) + (1 << 17)); // 1 MB
    float* part    = (float*)(ws + (size_t)(4 << 20));            // 4 MB @ 4M
    _Float16* featT = (_Float16*)(ws + (size_t)(8 << 20));        // 128 MB @ 8M

    transpose_cast_W1T_kernel<<<dim3(4, 16), 256, 0, stream>>>(W1, W1T);
    proj_h_partial_kernel<<<dim3(4, 8), 256, 0, stream>>>(hidden, W2, pph);
    proj_h_combine_kernel<<<4, 256, 0, stream>>>(pph, b1, b2, ph);
    precastT_kernel<<<2048, 256, 0, stream>>>(features, featT);

    gemm_logits_v9_kernel<<<1024, 1024, 0, stream>>>(featT, W1T, ph, V, part);

    softmax_kernel<<<B_, 256, 0, stream>>>(part, w_out);
    context_v8_kernel<<<dim3(B_, 8), 256, 0, stream>>>(featT, w_out, ctx_out);
}

// Round 11
// 314.502 us; speedup vs baseline: 1.1218x; 1.1218x over previous
//
#include <hip/hip_runtime.h>
#include <hip/hip_bf16.h>
#include <hip/hip_fp16.h>

#define B_ 32
#define T_ 2048
#define D_ 1024
#define U_ 1024
#define M_ (B_ * T_)   // 65536
#define NT_ 16         // U_/64 col slabs

typedef _Float16 f16x8 __attribute__((ext_vector_type(8)));
typedef float f32x4 __attribute__((ext_vector_type(4)));

__device__ __forceinline__ float fast_tanh(float x) {
    float xc = fminf(fmaxf(x, -10.f), 10.f);
    float e = __expf(2.f * xc);
    return 1.f - 2.f / (e + 1.f);
}

__device__ __forceinline__ void load_lds16(const void* g, void* l) {
    __builtin_amdgcn_global_load_lds(
        (const __attribute__((address_space(1))) void*)g,
        (__attribute__((address_space(3))) void*)l, 16, 0, 0);
}

// ---- precastT: features [M][D] f32 -> featT [M/16][D/8][16 slot][8] f16 ----
// (r9-verified) Coalesced reads -> XOR-swizzled LDS -> coalesced frag-order writes.
__global__ void precastT_kernel(const float* __restrict__ in,
                                _Float16* __restrict__ out) {
    __shared__ __align__(16) _Float16 lds[16 * 1024];   // 32 KB
    int mt = blockIdx.x;              // 4096 tiles of 16 rows
    int t = threadIdx.x;              // 256
    const float* src = in + (size_t)mt * 16384;
    #pragma unroll
    for (int i = 0; i < 4; ++i) {
        int o = (i * 256 + t) * 16;
        int r = o >> 10, c = o & 1023;
        f32x4 a0 = *(const f32x4*)(src + o);
        f32x4 a1 = *(const f32x4*)(src + o + 4);
        f32x4 a2 = *(const f32x4*)(src + o + 8);
        f32x4 a3 = *(const f32x4*)(src + o + 12);
        f16x8 h0, h1;
        h0[0]=(_Float16)a0[0]; h0[1]=(_Float16)a0[1]; h0[2]=(_Float16)a0[2]; h0[3]=(_Float16)a0[3];
        h0[4]=(_Float16)a1[0]; h0[5]=(_Float16)a1[1]; h0[6]=(_Float16)a1[2]; h0[7]=(_Float16)a1[3];
        h1[0]=(_Float16)a2[0]; h1[1]=(_Float16)a2[1]; h1[2]=(_Float16)a2[2]; h1[3]=(_Float16)a2[3];
        h1[4]=(_Float16)a3[0]; h1[5]=(_Float16)a3[1]; h1[6]=(_Float16)a3[2]; h1[7]=(_Float16)a3[3];
        int u0 = c >> 3, swz = r & 7;
        *(f16x8*)((char*)lds + r * 2048 + ((u0 ^ swz) << 4)) = h0;
        *(f16x8*)((char*)lds + r * 2048 + (((u0 + 1) ^ swz) << 4)) = h1;
    }
    __syncthreads();
    int slot = t & 15, kb0 = t >> 4, ssw = slot & 7;
    _Float16* dst = out + (size_t)mt * 16384 + slot * 8;
    #pragma unroll
    for (int i = 0; i < 8; ++i) {
        int kb = kb0 + i * 16;
        f16x8 h = *(const f16x8*)((char*)lds + slot * 2048 + ((kb ^ ssw) << 4));
        *(f16x8*)(dst + kb * 128) = h;
    }
}

// ---- W1 [D][U] f32 -> W1T tiled [U/16][D/8][16 slot][8] f16 (r9-verified) ----
__global__ void transpose_cast_W1T_kernel(const float* __restrict__ W1,
                                          _Float16* __restrict__ W1T) {
    int u = blockIdx.x * 256 + threadIdx.x;   // grid.x = 4
    int d0 = blockIdx.y * 64;                 // grid.y = 16
    _Float16* dst = W1T + (size_t)(u >> 4) * 16384 + (u & 15) * 8;
    for (int j8 = 0; j8 < 8; ++j8) {
        f16x8 h;
        #pragma unroll
        for (int j = 0; j < 8; ++j)
            h[j] = (_Float16)W1[(size_t)(d0 + j8 * 8 + j) * U_ + u];
        *(f16x8*)(dst + (size_t)(d0 / 8 + j8) * 128) = h;
    }
}

// ---------------- proj_h ----------------
__global__ void proj_h_partial_kernel(const float* __restrict__ hidden,
                                      const float* __restrict__ W2,
                                      float* __restrict__ pph) {
    int u = blockIdx.x * 256 + threadIdx.x;   // grid.x = 4
    int c = blockIdx.y;                       // grid.y = 8
    __shared__ float hb[32][128];
    for (int i = threadIdx.x; i < 32 * 128; i += 256)
        hb[i >> 7][i & 127] = hidden[(i >> 7) * D_ + c * 128 + (i & 127)];
    __syncthreads();
    float acc[32] = {};
    for (int d = 0; d < 128; ++d) {
        float w = W2[(size_t)(c * 128 + d) * U_ + u];
        #pragma unroll
        for (int b = 0; b < 32; ++b) acc[b] = fmaf(hb[b][d], w, acc[b]);
    }
    #pragma unroll
    for (int b = 0; b < 32; ++b)
        pph[((size_t)c * 32 + b) * U_ + u] = acc[b];
}

__global__ void proj_h_combine_kernel(const float* __restrict__ pph,
                                      const float* __restrict__ b1,
                                      const float* __restrict__ b2,
                                      float* __restrict__ ph) {
    int u = blockIdx.x * 256 + threadIdx.x;
    float bias = b1[u] + b2[u];
    for (int b = 0; b < 32; ++b) {
        float s = bias;
        #pragma unroll
        for (int c = 0; c < 8; ++c) s += pph[((size_t)c * 32 + b) * U_ + u];
        ph[b * U_ + u] = s;
    }
}

// ============ v10: persistent barrier-free GEMM, full dbuf ============
// Grid 256 (1 block/CU), 1024 thr = 16 waves -> 4 waves/SIMD.
// Block: fixed nt (64 u-cols), 8 sub-chunks of 512 rows (same XCD A-panel).
// Wave tile 32x64: acc[2][4] = 32 AGPR; af+bf BOTH double-buffered (1-step
// lookahead ~620 CU-cyc). B-slab (128KB W1T, 4 u-tiles) staged ONCE.
// Zero barriers after the single prologue barrier.

#define MFMA8(AF, BF) do { \
    __builtin_amdgcn_s_setprio(1); \
    _Pragma("unroll") \
    for (int m_ = 0; m_ < 2; ++m_) \
        _Pragma("unroll") \
        for (int n_ = 0; n_ < 4; ++n_) \
            acc[m_][n_] = __builtin_amdgcn_mfma_f32_16x16x32_f16( \
                AF[m_], BF[n_], acc[m_][n_], 0, 0, 0); \
    __builtin_amdgcn_s_setprio(0); \
} while (0)

#define LOAD_AF(dst, base, s) do { \
    dst[0] = *(const f16x8*)((base) + (s) * 1024); \
    dst[1] = *(const f16x8*)((base) + 32768 + (s) * 1024); \
} while (0)

#define READ_BF(dst, s) do { \
    _Pragma("unroll") \
    for (int n_ = 0; n_ < 4; ++n_) \
        dst[n_] = *(const f16x8*)(lB + n_ * 32768 + (s) * 1024 + l16); \
} while (0)

__global__ __launch_bounds__(1024, 4)
void gemm_logits_v10_kernel(const _Float16* __restrict__ featT,
                            const _Float16* __restrict__ W1T,
                            const float* __restrict__ ph,
                            const float* __restrict__ V,
                            float* __restrict__ part)   // [NT_][M]
{
    __shared__ __align__(16) _Float16 Bs[65536];   // 128 KB

    int bid = blockIdx.x;                 // 256
    int xcd = bid & 7, cu = bid >> 3;     // cu 0..31
    int nt = cu & 15, half = cu >> 4;     // nt 0..15, half 0..1
    int mgp0 = xcd * 16 + half * 8;       // first 512-row group (8 per block)

    int tid = threadIdx.x;
    int l = tid & 63, w = tid >> 6;       // 16 waves
    int l16 = l * 16;
    const char* lB = (const char*)Bs;
    const char* fT = (const char*)featT;

    // ---- B prologue: stage 128KB W1T slab ONCE, linear ----
    {
        const char* src = (const char*)W1T + (size_t)nt * 131072;
        #pragma unroll
        for (int i = 0; i < 8; ++i)
            load_lds16(src + i * 16384 + tid * 16, (char*)Bs + i * 16384 + tid * 16);
    }

    float Vv[4];
    #pragma unroll
    for (int n = 0; n < 4; ++n) Vv[n] = V[nt * 64 + n * 16 + (l & 15)];

    f16x8 afA[2], afB[2], bfA[4], bfB[4];
    f32x4 acc[2][4] = {};

    // chunk c A-base: tiles (mgp0+c)*32 + w*2 + {0,1}, tile stride 32KB
    const char* aCur = fT + ((size_t)((mgp0 * 32) + w * 2) << 15) + l16;
    LOAD_AF(afA, aCur, 0);

    asm volatile("s_waitcnt vmcnt(0)" ::: "memory");
    __builtin_amdgcn_s_barrier();   // the only block-wide barrier

    READ_BF(bfA, 0);

    #pragma unroll 1
    for (int c = 0; c < 8; ++c) {
        const char* aNext = fT + ((size_t)(((mgp0 + (c < 7 ? c + 1 : c)) * 32) + w * 2) << 15) + l16;

        #pragma unroll 1
        for (int s = 0; s < 32; s += 2) {
            LOAD_AF(afB, aCur, s + 1);
            READ_BF(bfB, s + 1);
            MFMA8(afA, bfA);
            if (s < 30) LOAD_AF(afA, aCur, s + 2);
            else        LOAD_AF(afA, aNext, 0);          // cross-chunk prefetch
            READ_BF(bfA, (s + 2) & 31);                  // B wraps (same slab)
            MFMA8(afB, bfB);
        }

        // ---- epilogue chunk c: s = tanh(acc + ph), partial = sum_u s*V ----
        int row0 = (mgp0 + c) * 512 + w * 32;
        const float* phb = ph + ((mgp0 + c) >> 2) * U_;   // batch = 4 chunks
        float phv[4];
        #pragma unroll
        for (int n = 0; n < 4; ++n) phv[n] = phb[nt * 64 + n * 16 + (l & 15)];
        #pragma unroll
        for (int m = 0; m < 2; ++m) {
            #pragma unroll
            for (int r = 0; r < 4; ++r) {
                float p = 0.f;
                #pragma unroll
                for (int n = 0; n < 4; ++n)
                    p = fmaf(fast_tanh(acc[m][n][r] + phv[n]), Vv[n], p);
                p += __shfl_xor(p, 1, 64);
                p += __shfl_xor(p, 2, 64);
                p += __shfl_xor(p, 4, 64);
                p += __shfl_xor(p, 8, 64);
                if ((l & 15) == 0)
                    part[(size_t)nt * M_ + row0 + m * 16 + (l >> 4) * 4 + r] = p;
            }
        }
        #pragma unroll
        for (int m = 0; m < 2; ++m)
            #pragma unroll
            for (int n = 0; n < 4; ++n)
                acc[m][n] = (f32x4){0.f, 0.f, 0.f, 0.f};
        aCur = aNext;
    }
}

// ---------------- softmax over T per batch ----------------
__global__ void softmax_kernel(const float* __restrict__ part,
                               float* __restrict__ wout) {
    int b = blockIdx.x;
    int tid = threadIdx.x;
    __shared__ float red[8];
    float lg[8];
    #pragma unroll
    for (int j = 0; j < 8; ++j) {
        int t = tid + j * 256;
        float s = 0.f;
        #pragma unroll
        for (int p = 0; p < NT_; ++p)
            s += part[(size_t)p * M_ + b * T_ + t];
        lg[j] = s;
    }
    float mx = lg[0];
    #pragma unroll
    for (int j = 1; j < 8; ++j) mx = fmaxf(mx, lg[j]);
    #pragma unroll
    for (int off = 1; off < 64; off <<= 1) mx = fmaxf(mx, __shfl_xor(mx, off, 64));
    int wv = tid >> 6;
    if ((tid & 63) == 0) red[wv] = mx;
    __syncthreads();
    mx = fmaxf(fmaxf(red[0], red[1]), fmaxf(red[2], red[3]));
    float e[8];
    float sum = 0.f;
    #pragma unroll
    for (int j = 0; j < 8; ++j) { e[j] = __expf(lg[j] - mx); sum += e[j]; }
    #pragma unroll
    for (int off = 1; off < 64; off <<= 1) sum += __shfl_xor(sum, off, 64);
    if ((tid & 63) == 0) red[4 + wv] = sum;
    __syncthreads();
    sum = red[4] + red[5] + red[6] + red[7];
    float inv = 1.f / sum;
    #pragma unroll
    for (int j = 0; j < 8; ++j)
        wout[b * T_ + tid + j * 256] = e[j] * inv;
}

// ---- context from featT (tiled, r9-verified): grid (32 b, 8 dchunk) ----
__global__ void context_v7_kernel(const _Float16* __restrict__ featT,
                                  const float* __restrict__ w,
                                  float* __restrict__ ctx) {
    int b = blockIdx.x;        // 32
    int dc = blockIdx.y;       // 8 (128 d each)
    int t = threadIdx.x;       // 256
    __shared__ float wLds[2048];
    for (int i = t; i < 2048; i += 256) wLds[i] = w[b * T_ + i];
    __syncthreads();

    float acc[8] = {};
    const char* base = (const char*)featT + (size_t)b * 128 * 32768 + dc * 4096 + t * 16;
    int slot = t & 15;
    #pragma unroll 4
    for (int mt = 0; mt < 128; ++mt) {
        f16x8 v = *(const f16x8*)(base + (size_t)mt * 32768);
        float wt = wLds[mt * 16 + slot];
        #pragma unroll
        for (int j = 0; j < 8; ++j) acc[j] = fmaf(wt, (float)v[j], acc[j]);
    }
    #pragma unroll
    for (int j = 0; j < 8; ++j) {
        acc[j] += __shfl_xor(acc[j], 1, 64);
        acc[j] += __shfl_xor(acc[j], 2, 64);
        acc[j] += __shfl_xor(acc[j], 4, 64);
        acc[j] += __shfl_xor(acc[j], 8, 64);
    }
    if ((t & 15) == 0) {
        float* o = ctx + b * D_ + dc * 128 + (t >> 4) * 8;
        #pragma unroll
        for (int j = 0; j < 8; ++j) o[j] = acc[j];
    }
}

extern "C" void kernel_launch(void* const* d_in, const int* in_sizes, int n_in,
                              void* d_out, int out_size, void* d_ws, size_t ws_size,
                              hipStream_t stream) {
    const float* features = (const float*)d_in[0];
    const float* hidden   = (const float*)d_in[1];
    const float* W1       = (const float*)d_in[2];
    const float* b1       = (const float*)d_in[3];
    const float* W2       = (const float*)d_in[4];
    const float* b2       = (const float*)d_in[5];
    const float* V        = (const float*)d_in[6];
    // bV drops out of softmax (shift-invariant).

    float* ctx_out = (float*)d_out;            // [B,D]
    float* w_out   = ctx_out + B_ * D_;        // [B,T,1]

    char* ws = (char*)d_ws;
    _Float16* W1T  = (_Float16*)ws;                               // 2 MB @ 0
    float* ph      = (float*)(ws + (size_t)(2 << 20));            // 128 KB @ 2M
    float* pph     = (float*)(ws + (size_t)(2 << 20) + (1 << 17)); // 1 MB
    float* part    = (float*)(ws + (size_t)(4 << 20));            // 4 MB @ 4M
    _Float16* featT = (_Float16*)(ws + (size_t)(8 << 20));        // 128 MB @ 8M

    transpose_cast_W1T_kernel<<<dim3(4, 16), 256, 0, stream>>>(W1, W1T);
    proj_h_partial_kernel<<<dim3(4, 8), 256, 0, stream>>>(hidden, W2, pph);
    proj_h_combine_kernel<<<4, 256, 0, stream>>>(pph, b1, b2, ph);
    precastT_kernel<<<4096, 256, 0, stream>>>(features, featT);

    gemm_logits_v10_kernel<<<256, 1024, 0, stream>>>(featT, W1T, ph, V, part);

    softmax_kernel<<<B_, 256, 0, stream>>>(part, w_out);
    context_v7_kernel<<<dim3(B_, 8), 256, 0, stream>>>(featT, w_out, ctx_out);
}

// Round 12
// 306.051 us; speedup vs baseline: 1.1528x; 1.0276x over previous
//
#include <hip/hip_runtime.h>
#include <hip/hip_bf16.h>
#include <hip/hip_fp16.h>

#define B_ 32
#define T_ 2048
#define D_ 1024
#define U_ 1024
#define M_ (B_ * T_)   // 65536
#define NT_ 16         // U_/64 col slabs

typedef _Float16 f16x8 __attribute__((ext_vector_type(8)));
typedef float f32x4 __attribute__((ext_vector_type(4)));

__device__ __forceinline__ float fast_tanh(float x) {
    // no clamp: e=+inf -> 1, e=0 -> -1 (limits exact)
    float e = __expf(2.f * x);
    return 1.f - 2.f / (e + 1.f);
}

__device__ __forceinline__ void load_lds16(const void* g, void* l) {
    __builtin_amdgcn_global_load_lds(
        (const __attribute__((address_space(1))) void*)g,
        (__attribute__((address_space(3))) void*)l, 16, 0, 0);
}

// ---- precastT: features [M][D] f32 -> featT [M/16][D/8][16 slot][8] f16 ----
// (r9-verified) Coalesced reads -> XOR-swizzled LDS -> coalesced frag-order writes.
__global__ void precastT_kernel(const float* __restrict__ in,
                                _Float16* __restrict__ out) {
    __shared__ __align__(16) _Float16 lds[16 * 1024];   // 32 KB
    int mt = blockIdx.x;              // 4096 tiles of 16 rows
    int t = threadIdx.x;              // 256
    const float* src = in + (size_t)mt * 16384;
    #pragma unroll
    for (int i = 0; i < 4; ++i) {
        int o = (i * 256 + t) * 16;
        int r = o >> 10, c = o & 1023;
        f32x4 a0 = *(const f32x4*)(src + o);
        f32x4 a1 = *(const f32x4*)(src + o + 4);
        f32x4 a2 = *(const f32x4*)(src + o + 8);
        f32x4 a3 = *(const f32x4*)(src + o + 12);
        f16x8 h0, h1;
        h0[0]=(_Float16)a0[0]; h0[1]=(_Float16)a0[1]; h0[2]=(_Float16)a0[2]; h0[3]=(_Float16)a0[3];
        h0[4]=(_Float16)a1[0]; h0[5]=(_Float16)a1[1]; h0[6]=(_Float16)a1[2]; h0[7]=(_Float16)a1[3];
        h1[0]=(_Float16)a2[0]; h1[1]=(_Float16)a2[1]; h1[2]=(_Float16)a2[2]; h1[3]=(_Float16)a2[3];
        h1[4]=(_Float16)a3[0]; h1[5]=(_Float16)a3[1]; h1[6]=(_Float16)a3[2]; h1[7]=(_Float16)a3[3];
        int u0 = c >> 3, swz = r & 7;
        *(f16x8*)((char*)lds + r * 2048 + ((u0 ^ swz) << 4)) = h0;
        *(f16x8*)((char*)lds + r * 2048 + (((u0 + 1) ^ swz) << 4)) = h1;
    }
    __syncthreads();
    int slot = t & 15, kb0 = t >> 4, ssw = slot & 7;
    _Float16* dst = out + (size_t)mt * 16384 + slot * 8;
    #pragma unroll
    for (int i = 0; i < 8; ++i) {
        int kb = kb0 + i * 16;
        f16x8 h = *(const f16x8*)((char*)lds + slot * 2048 + ((kb ^ ssw) << 4));
        *(f16x8*)(dst + kb * 128) = h;
    }
}

// ---- W1 [D][U] f32 -> W1T tiled [U/16][D/8][16 slot][8] f16 (r9-verified) ----
__global__ void transpose_cast_W1T_kernel(const float* __restrict__ W1,
                                          _Float16* __restrict__ W1T) {
    int u = blockIdx.x * 256 + threadIdx.x;   // grid.x = 4
    int d0 = blockIdx.y * 64;                 // grid.y = 16
    _Float16* dst = W1T + (size_t)(u >> 4) * 16384 + (u & 15) * 8;
    for (int j8 = 0; j8 < 8; ++j8) {
        f16x8 h;
        #pragma unroll
        for (int j = 0; j < 8; ++j)
            h[j] = (_Float16)W1[(size_t)(d0 + j8 * 8 + j) * U_ + u];
        *(f16x8*)(dst + (size_t)(d0 / 8 + j8) * 128) = h;
    }
}

// ---------------- proj_h ----------------
__global__ void proj_h_partial_kernel(const float* __restrict__ hidden,
                                      const float* __restrict__ W2,
                                      float* __restrict__ pph) {
    int u = blockIdx.x * 256 + threadIdx.x;   // grid.x = 4
    int c = blockIdx.y;                       // grid.y = 8
    __shared__ float hb[32][128];
    for (int i = threadIdx.x; i < 32 * 128; i += 256)
        hb[i >> 7][i & 127] = hidden[(i >> 7) * D_ + c * 128 + (i & 127)];
    __syncthreads();
    float acc[32] = {};
    for (int d = 0; d < 128; ++d) {
        float w = W2[(size_t)(c * 128 + d) * U_ + u];
        #pragma unroll
        for (int b = 0; b < 32; ++b) acc[b] = fmaf(hb[b][d], w, acc[b]);
    }
    #pragma unroll
    for (int b = 0; b < 32; ++b)
        pph[((size_t)c * 32 + b) * U_ + u] = acc[b];
}

__global__ void proj_h_combine_kernel(const float* __restrict__ pph,
                                      const float* __restrict__ b1,
                                      const float* __restrict__ b2,
                                      float* __restrict__ ph) {
    int u = blockIdx.x * 256 + threadIdx.x;
    float bias = b1[u] + b2[u];
    for (int b = 0; b < 32; ++b) {
        float s = bias;
        #pragma unroll
        for (int c = 0; c < 8; ++c) s += pph[((size_t)c * 32 + b) * U_ + u];
        ph[b * U_ + u] = s;
    }
}

// ============ v11: v10 + fully-unrolled K-loop (imm offsets) ============
// Grid 256 (1 block/CU), 1024 thr = 16 waves -> 4 waves/SIMD.
// Block: fixed nt (64 u-cols), 8 sub-chunks of 512 rows. Wave tile 32x64.
// af+bf double-buffered; B-slab (128KB) staged once; zero K-loop barriers.
// Inner K-loop fully unrolled: ds_read offsets are 16-bit immediates
// (two bases keep n*32768+s*1024 <= 64512), global offsets compile-time.

#define MFMA8(AF, BF) do { \
    __builtin_amdgcn_s_setprio(1); \
    _Pragma("unroll") \
    for (int m_ = 0; m_ < 2; ++m_) \
        _Pragma("unroll") \
        for (int n_ = 0; n_ < 4; ++n_) \
            acc[m_][n_] = __builtin_amdgcn_mfma_f32_16x16x32_f16( \
                AF[m_], BF[n_], acc[m_][n_], 0, 0, 0); \
    __builtin_amdgcn_s_setprio(0); \
} while (0)

#define LOAD_AF(dst, base, s) do { \
    dst[0] = *(const f16x8*)((base) + (s) * 1024); \
    dst[1] = *(const f16x8*)((base) + 32768 + (s) * 1024); \
} while (0)

#define READ_BF(dst, s) do { \
    dst[0] = *(const f16x8*)(lB0 + (s) * 1024); \
    dst[1] = *(const f16x8*)(lB0 + 32768 + (s) * 1024); \
    dst[2] = *(const f16x8*)(lB1 + (s) * 1024); \
    dst[3] = *(const f16x8*)(lB1 + 32768 + (s) * 1024); \
} while (0)

__global__ __launch_bounds__(1024, 4)
void gemm_logits_v11_kernel(const _Float16* __restrict__ featT,
                            const _Float16* __restrict__ W1T,
                            const float* __restrict__ ph,
                            const float* __restrict__ V,
                            float* __restrict__ part)   // [NT_][M]
{
    __shared__ __align__(16) _Float16 Bs[65536];   // 128 KB

    int bid = blockIdx.x;                 // 256
    int xcd = bid & 7, cu = bid >> 3;     // cu 0..31
    int nt = cu & 15, half = cu >> 4;     // nt 0..15, half 0..1
    int mgp0 = xcd * 16 + half * 8;       // first 512-row group (8 per block)

    int tid = threadIdx.x;
    int l = tid & 63, w = tid >> 6;       // 16 waves
    int l16 = l * 16;
    const char* fT = (const char*)featT;

    // ---- B prologue: stage 128KB W1T slab ONCE, linear ----
    {
        const char* src = (const char*)W1T + (size_t)nt * 131072;
        #pragma unroll
        for (int i = 0; i < 8; ++i)
            load_lds16(src + i * 16384 + tid * 16, (char*)Bs + i * 16384 + tid * 16);
    }

    // ds_read bases: offsets n2*32768 + s*1024 stay within 16-bit imm
    const char* lB0 = (const char*)Bs + l16;
    const char* lB1 = (const char*)Bs + 65536 + l16;

    float Vv[4];
    #pragma unroll
    for (int n = 0; n < 4; ++n) Vv[n] = V[nt * 64 + n * 16 + (l & 15)];

    f16x8 afA[2], afB[2], bfA[4], bfB[4];
    f32x4 acc[2][4] = {};

    const char* aCur = fT + ((size_t)((mgp0 * 32) + w * 2) << 15) + l16;
    LOAD_AF(afA, aCur, 0);

    asm volatile("s_waitcnt vmcnt(0)" ::: "memory");
    __builtin_amdgcn_s_barrier();   // the only block-wide barrier

    READ_BF(bfA, 0);

    #pragma unroll 1
    for (int c = 0; c < 8; ++c) {
        const char* aNext = fT + ((size_t)(((mgp0 + (c < 7 ? c + 1 : c)) * 32) + w * 2) << 15) + l16;

        #pragma unroll
        for (int s = 0; s < 32; s += 2) {
            LOAD_AF(afB, aCur, s + 1);
            READ_BF(bfB, s + 1);
            MFMA8(afA, bfA);
            if (s < 30) LOAD_AF(afA, aCur, s + 2);
            else        LOAD_AF(afA, aNext, 0);          // cross-chunk prefetch
            READ_BF(bfA, (s + 2) & 31);                  // wraps (compile-time)
            MFMA8(afB, bfB);
        }

        // ---- epilogue chunk c: s = tanh(acc + ph), partial = sum_u s*V ----
        int row0 = (mgp0 + c) * 512 + w * 32;
        const float* phb = ph + ((mgp0 + c) >> 2) * U_;   // batch = 4 chunks
        float phv[4];
        #pragma unroll
        for (int n = 0; n < 4; ++n) phv[n] = phb[nt * 64 + n * 16 + (l & 15)];
        #pragma unroll
        for (int m = 0; m < 2; ++m) {
            #pragma unroll
            for (int r = 0; r < 4; ++r) {
                float p = 0.f;
                #pragma unroll
                for (int n = 0; n < 4; ++n)
                    p = fmaf(fast_tanh(acc[m][n][r] + phv[n]), Vv[n], p);
                p += __shfl_xor(p, 1, 64);
                p += __shfl_xor(p, 2, 64);
                p += __shfl_xor(p, 4, 64);
                p += __shfl_xor(p, 8, 64);
                if ((l & 15) == 0)
                    part[(size_t)nt * M_ + row0 + m * 16 + (l >> 4) * 4 + r] = p;
            }
        }
        #pragma unroll
        for (int m = 0; m < 2; ++m)
            #pragma unroll
            for (int n = 0; n < 4; ++n)
                acc[m][n] = (f32x4){0.f, 0.f, 0.f, 0.f};
        aCur = aNext;
    }
}

// ---------------- softmax over T per batch ----------------
__global__ void softmax_kernel(const float* __restrict__ part,
                               float* __restrict__ wout) {
    int b = blockIdx.x;
    int tid = threadIdx.x;
    __shared__ float red[8];
    float lg[8];
    #pragma unroll
    for (int j = 0; j < 8; ++j) {
        int t = tid + j * 256;
        float s = 0.f;
        #pragma unroll
        for (int p = 0; p < NT_; ++p)
            s += part[(size_t)p * M_ + b * T_ + t];
        lg[j] = s;
    }
    float mx = lg[0];
    #pragma unroll
    for (int j = 1; j < 8; ++j) mx = fmaxf(mx, lg[j]);
    #pragma unroll
    for (int off = 1; off < 64; off <<= 1) mx = fmaxf(mx, __shfl_xor(mx, off, 64));
    int wv = tid >> 6;
    if ((tid & 63) == 0) red[wv] = mx;
    __syncthreads();
    mx = fmaxf(fmaxf(red[0], red[1]), fmaxf(red[2], red[3]));
    float e[8];
    float sum = 0.f;
    #pragma unroll
    for (int j = 0; j < 8; ++j) { e[j] = __expf(lg[j] - mx); sum += e[j]; }
    #pragma unroll
    for (int off = 1; off < 64; off <<= 1) sum += __shfl_xor(sum, off, 64);
    if ((tid & 63) == 0) red[4 + wv] = sum;
    __syncthreads();
    sum = red[4] + red[5] + red[6] + red[7];
    float inv = 1.f / sum;
    #pragma unroll
    for (int j = 0; j < 8; ++j)
        wout[b * T_ + tid + j * 256] = e[j] * inv;
}

// ---- context from featT (tiled, r9-verified): grid (32 b, 8 dchunk) ----
__global__ void context_v7_kernel(const _Float16* __restrict__ featT,
                                  const float* __restrict__ w,
                                  float* __restrict__ ctx) {
    int b = blockIdx.x;        // 32
    int dc = blockIdx.y;       // 8 (128 d each)
    int t = threadIdx.x;       // 256
    __shared__ float wLds[2048];
    for (int i = t; i < 2048; i += 256) wLds[i] = w[b * T_ + i];
    __syncthreads();

    float acc[8] = {};
    const char* base = (const char*)featT + (size_t)b * 128 * 32768 + dc * 4096 + t * 16;
    int slot = t & 15;
    #pragma unroll 4
    for (int mt = 0; mt < 128; ++mt) {
        f16x8 v = *(const f16x8*)(base + (size_t)mt * 32768);
        float wt = wLds[mt * 16 + slot];
        #pragma unroll
        for (int j = 0; j < 8; ++j) acc[j] = fmaf(wt, (float)v[j], acc[j]);
    }
    #pragma unroll
    for (int j = 0; j < 8; ++j) {
        acc[j] += __shfl_xor(acc[j], 1, 64);
        acc[j] += __shfl_xor(acc[j], 2, 64);
        acc[j] += __shfl_xor(acc[j], 4, 64);
        acc[j] += __shfl_xor(acc[j], 8, 64);
    }
    if ((t & 15) == 0) {
        float* o = ctx + b * D_ + dc * 128 + (t >> 4) * 8;
        #pragma unroll
        for (int j = 0; j < 8; ++j) o[j] = acc[j];
    }
}

extern "C" void kernel_launch(void* const* d_in, const int* in_sizes, int n_in,
                              void* d_out, int out_size, void* d_ws, size_t ws_size,
                              hipStream_t stream) {
    const float* features = (const float*)d_in[0];
    const float* hidden   = (const float*)d_in[1];
    const float* W1       = (const float*)d_in[2];
    const float* b1       = (const float*)d_in[3];
    const float* W2       = (const float*)d_in[4];
    const float* b2       = (const float*)d_in[5];
    const float* V        = (const float*)d_in[6];
    // bV drops out of softmax (shift-invariant).

    float* ctx_out = (float*)d_out;            // [B,D]
    float* w_out   = ctx_out + B_ * D_;        // [B,T,1]

    char* ws = (char*)d_ws;
    _Float16* W1T  = (_Float16*)ws;                               // 2 MB @ 0
    float* ph      = (float*)(ws + (size_t)(2 << 20));            // 128 KB @ 2M
    float* pph     = (float*)(ws + (size_t)(2 << 20) + (1 << 17)); // 1 MB
    float* part    = (float*)(ws + (size_t)(4 << 20));            // 4 MB @ 4M
    _Float16* featT = (_Float16*)(ws + (size_t)(8 << 20));        // 128 MB @ 8M

    transpose_cast_W1T_kernel<<<dim3(4, 16), 256, 0, stream>>>(W1, W1T);
    proj_h_partial_kernel<<<dim3(4, 8), 256, 0, stream>>>(hidden, W2, pph);
    proj_h_combine_kernel<<<4, 256, 0, stream>>>(pph, b1, b2, ph);
    precastT_kernel<<<4096, 256, 0, stream>>>(features, featT);

    gemm_logits_v11_kernel<<<256, 1024, 0, stream>>>(featT, W1T, ph, V, part);

    softmax_kernel<<<B_, 256, 0, stream>>>(part, w_out);
    context_v7_kernel<<<dim3(B_, 8), 256, 0, stream>>>(featT, w_out, ctx_out);
}